// Round 12
// baseline (231.526 us; speedup 1.0000x reference)
//
#include <hip/hip_runtime.h>
#include <hip/hip_bf16.h>

#define S_LEN 4096
#define NH    16
#define DD    128
#define HD    2048
#define QB    64
#define KB    64
#define NT    (S_LEN/KB)
#define SHN   (S_LEN*NH)    // 65536 q-rows

typedef __bf16 bf16_t;
typedef bf16_t bf16x8 __attribute__((ext_vector_type(8)));
typedef float  f32x4  __attribute__((ext_vector_type(4)));

static __device__ __forceinline__ bf16x8 pack8(float4 a, float4 b, float s) {
  bf16x8 v;
  v[0]=(bf16_t)(a.x*s); v[1]=(bf16_t)(a.y*s); v[2]=(bf16_t)(a.z*s); v[3]=(bf16_t)(a.w*s);
  v[4]=(bf16_t)(b.x*s); v[5]=(bf16_t)(b.y*s); v[6]=(bf16_t)(b.z*s); v[7]=(bf16_t)(b.w*s);
  return v;
}

// ---- prep K: fp32 [s][h][d] -> bf16 frag-major tiles [h][kt][f=(b,c)][lane][8] ----
__global__ __launch_bounds__(256) void prep_k(const float* __restrict__ Kg,
                                              bf16_t* __restrict__ Kp) {
  const int kt = blockIdx.x, h = blockIdx.y, tid = threadIdx.x;
  __shared__ bf16_t tile[KB][DD + 8];
  #pragma unroll
  for (int it = 0; it < 8; ++it) {
    int lin4 = it*256 + tid;
    int r  = lin4 >> 5;
    int dc = (lin4 & 31) * 4;
    float4 a = *(const float4*)(Kg + (size_t)(kt*KB + r)*HD + h*DD + dc);
    tile[r][dc+0]=(bf16_t)a.x; tile[r][dc+1]=(bf16_t)a.y;
    tile[r][dc+2]=(bf16_t)a.z; tile[r][dc+3]=(bf16_t)a.w;
  }
  __syncthreads();
  bf16_t* out = Kp + (size_t)(h*NT + kt)*8192;
  #pragma unroll
  for (int it = 0; it < 4; ++it) {
    int cid = it*256 + tid;
    int f = cid >> 6, l = cid & 63;
    int b = f >> 2, c = f & 3;
    int row = b*16 + (l & 15);
    int d0  = c*32 + (l >> 4)*8;
    bf16x8 v = *(const bf16x8*)(&tile[row][d0]);
    *(bf16x8*)(out + (size_t)cid*8) = v;
  }
}

// ---- prep V: fp32 [s][h][d] -> bf16 frag-major V^T tiles [h][kt][f=(ks,db)][lane][8] ----
__global__ __launch_bounds__(256) void prep_v(const float* __restrict__ Vg,
                                              bf16_t* __restrict__ Vp) {
  const int kt = blockIdx.x, h = blockIdx.y, tid = threadIdx.x;
  __shared__ bf16_t tile[KB][DD + 8];
  #pragma unroll
  for (int it = 0; it < 8; ++it) {
    int lin4 = it*256 + tid;
    int r  = lin4 >> 5;
    int dc = (lin4 & 31) * 4;
    float4 a = *(const float4*)(Vg + (size_t)(kt*KB + r)*HD + h*DD + dc);
    tile[r][dc+0]=(bf16_t)a.x; tile[r][dc+1]=(bf16_t)a.y;
    tile[r][dc+2]=(bf16_t)a.z; tile[r][dc+3]=(bf16_t)a.w;
  }
  __syncthreads();
  bf16_t* out = Vp + (size_t)(h*NT + kt)*8192;
  #pragma unroll
  for (int it = 0; it < 4; ++it) {
    int cid = it*256 + tid;
    int f = cid >> 6, l = cid & 63;
    int ks = f >> 3, db = f & 7;
    int d  = db*16 + (l & 15);
    int c0 = ks*32 + (l >> 4)*8;
    bf16x8 v;
    #pragma unroll
    for (int m = 0; m < 8; ++m) {
      int c = c0 + m;
      int k = 32*(c>>5) + 16*((c>>2)&1) + 4*((c>>3)&3) + (c&3);
      v[m] = tile[k][d];
    }
    *(bf16x8*)(out + (size_t)cid*8) = v;
  }
}

// ---- main: each block does half the KV range for one 64-row q-tile ----
__global__ __launch_bounds__(128, 2) void attn_fwd(const float* __restrict__ Qg,
                                                   const bf16_t* __restrict__ Kp,
                                                   const bf16_t* __restrict__ Vp,
                                                   float* __restrict__ A0,   // = d_out (raw partial 0)
                                                   float* __restrict__ A1,
                                                   float* __restrict__ lmW) {
  // chunked XCD swizzle: 2048 blocks, XCD x owns logical [x*256, x*256+256) = 2 heads
  const int phys = blockIdx.x;
  const int logical = (phys & 7) * 256 + (phys >> 3);
  const int h   = logical >> 7;
  const int rem = logical & 127;
  const int qt  = rem >> 1;          // q-tile of 64 rows
  const int p   = rem & 1;           // KV half
  const int tid  = threadIdx.x;
  const int wid  = tid >> 6;         // 0..1
  const int lane = tid & 63;
  const int l16  = lane & 15;
  const int lg   = lane >> 4;
  const int lo16 = lane * 16;
  const int kt0 = p * (NT/2), kt1 = kt0 + (NT/2);

  // ---- Q fragments for 2 q-groups (32 q-rows per wave) ----
  const float qs = 0.08838834764831845f * 1.4426950408889634f;
  bf16x8 qf[2][4];
  #pragma unroll
  for (int g = 0; g < 2; ++g) {
    const int qrow = qt*QB + wid*32 + g*16 + l16;
    const float* qp = Qg + (size_t)qrow*HD + h*DD + lg*8;
    #pragma unroll
    for (int c = 0; c < 4; ++c) {
      float4 a = *(const float4*)(qp + c*32);
      float4 b = *(const float4*)(qp + c*32 + 4);
      qf[g][c] = pack8(a, b, qs);
    }
  }
  bf16x8 onesf;
  #pragma unroll
  for (int j = 0; j < 8; ++j) onesf[j] = (bf16_t)1.0f;

  // ---- operand streams: frag-major, direct global->VGPR (L1/L2 resident) ----
  const char* KpH = (const char*)(Kp + (size_t)h*NT*8192) + lo16;
  const char* VpH = (const char*)(Vp + (size_t)h*NT*8192) + lo16;

  bf16x8 kreg[16];
  {
    const char* kg = KpH + (size_t)kt0*16384;
    #pragma unroll
    for (int f = 0; f < 16; ++f) kreg[f] = *(const bf16x8*)(kg + (f << 10));
  }

  f32x4 acc[2][8];
  f32x4 acc_l[2];
  #pragma unroll
  for (int g = 0; g < 2; ++g) {
    #pragma unroll
    for (int i = 0; i < 8; ++i) acc[g][i] = (f32x4){0.f,0.f,0.f,0.f};
    acc_l[g] = (f32x4){0.f,0.f,0.f,0.f};
  }
  float m_run[2] = {-__builtin_inff(), -__builtin_inff()};

  for (int kt = kt0; kt < kt1; ++kt) {
    // ---- S^T = K Q^T : 32 MFMA from kreg ----
    f32x4 sc[2][4];
    #pragma unroll
    for (int g = 0; g < 2; ++g)
      #pragma unroll
      for (int b = 0; b < 4; ++b) sc[g][b] = (f32x4){0.f,0.f,0.f,0.f};
    __builtin_amdgcn_s_setprio(1);
    #pragma unroll
    for (int b = 0; b < 4; ++b) {
      #pragma unroll
      for (int c = 0; c < 4; ++c) {
        bf16x8 kb = kreg[b*4 + c];
        sc[0][b] = __builtin_amdgcn_mfma_f32_16x16x32_bf16(kb, qf[0][c], sc[0][b], 0, 0, 0);
        sc[1][b] = __builtin_amdgcn_mfma_f32_16x16x32_bf16(kb, qf[1][c], sc[1][b], 0, 0, 0);
      }
    }
    __builtin_amdgcn_s_setprio(0);

    // ---- issue V first half (ks=0); hides under softmax ----
    const char* vt = VpH + (size_t)kt*16384;
    bf16x8 va0[8];
    #pragma unroll
    for (int f = 0; f < 8; ++f) va0[f] = *(const bf16x8*)(vt + (f << 10));

    // ---- refill kreg for next tile (WAR-safe: after QK issued) ----
    if (kt + 1 < kt1) {
      const char* kg = KpH + (size_t)(kt + 1)*16384;
      #pragma unroll
      for (int f = 0; f < 16; ++f) kreg[f] = *(const bf16x8*)(kg + (f << 10));
    }

    // ---- online softmax per q-group with defer-rescale (THR=8) ----
    bf16x8 pp[2][2];
    #pragma unroll
    for (int g = 0; g < 2; ++g) {
      float pmax;
      {
        float a0 = fmaxf(fmaxf(sc[g][0][0], sc[g][0][1]), sc[g][0][2]);
        float a1 = fmaxf(fmaxf(sc[g][0][3], sc[g][1][0]), sc[g][1][1]);
        float a2 = fmaxf(fmaxf(sc[g][1][2], sc[g][1][3]), sc[g][2][0]);
        float a3 = fmaxf(fmaxf(sc[g][2][1], sc[g][2][2]), sc[g][2][3]);
        float a4 = fmaxf(fmaxf(sc[g][3][0], sc[g][3][1]), sc[g][3][2]);
        float b0 = fmaxf(fmaxf(a0, a1), a2);
        float b1 = fmaxf(fmaxf(a3, a4), sc[g][3][3]);
        pmax = fmaxf(b0, b1);
        pmax = fmaxf(pmax, __shfl_xor(pmax, 16));
        pmax = fmaxf(pmax, __shfl_xor(pmax, 32));
      }
      if (!__all(pmax - m_run[g] <= 8.0f)) {
        float mnew  = fmaxf(m_run[g], pmax);
        float alpha = exp2f(m_run[g] - mnew);    // first tile: exp2(-inf)=0
        m_run[g] = mnew;
        #pragma unroll
        for (int i = 0; i < 8; ++i) {
          #pragma unroll
          for (int r = 0; r < 4; ++r) acc[g][i][r] *= alpha;
        }
        #pragma unroll
        for (int r = 0; r < 4; ++r) acc_l[g][r] *= alpha;
      }
      #pragma unroll
      for (int b = 0; b < 4; ++b) {
        #pragma unroll
        for (int r = 0; r < 4; ++r) {
          float pv = exp2f(sc[g][b][r] - m_run[g]);   // bounded by 2^8
          pp[g][b >> 1][(b & 1)*4 + r] = (bf16_t)pv;
        }
      }
    }

    // ---- issue V second half (ks=1); hides under PV ks=0 ----
    bf16x8 va1[8];
    #pragma unroll
    for (int f = 0; f < 8; ++f) va1[f] = *(const bf16x8*)(vt + ((8 + f) << 10));

    // ---- O^T += V^T P^T ; l += 1^T P^T : 36 MFMA, pure-register ----
    __builtin_amdgcn_s_setprio(1);
    acc_l[0] = __builtin_amdgcn_mfma_f32_16x16x32_bf16(onesf, pp[0][0], acc_l[0], 0, 0, 0);
    acc_l[1] = __builtin_amdgcn_mfma_f32_16x16x32_bf16(onesf, pp[1][0], acc_l[1], 0, 0, 0);
    #pragma unroll
    for (int db = 0; db < 8; ++db) {
      acc[0][db] = __builtin_amdgcn_mfma_f32_16x16x32_bf16(va0[db], pp[0][0], acc[0][db], 0, 0, 0);
      acc[1][db] = __builtin_amdgcn_mfma_f32_16x16x32_bf16(va0[db], pp[1][0], acc[1][db], 0, 0, 0);
    }
    acc_l[0] = __builtin_amdgcn_mfma_f32_16x16x32_bf16(onesf, pp[0][1], acc_l[0], 0, 0, 0);
    acc_l[1] = __builtin_amdgcn_mfma_f32_16x16x32_bf16(onesf, pp[1][1], acc_l[1], 0, 0, 0);
    #pragma unroll
    for (int db = 0; db < 8; ++db) {
      acc[0][db] = __builtin_amdgcn_mfma_f32_16x16x32_bf16(va1[db], pp[0][1], acc[0][db], 0, 0, 0);
      acc[1][db] = __builtin_amdgcn_mfma_f32_16x16x32_bf16(va1[db], pp[1][1], acc[1][db], 0, 0, 0);
    }
    __builtin_amdgcn_s_setprio(0);
  }

  // ---- epilogue: store RAW partial acc + (l, m) per q-row ----
  float* Ap = p ? A1 : A0;
  #pragma unroll
  for (int g = 0; g < 2; ++g) {
    const int qrow = qt*QB + wid*32 + g*16 + l16;
    float* op = Ap + (size_t)qrow*HD + h*DD + lg*4;
    #pragma unroll
    for (int db = 0; db < 8; ++db) {
      float4 o;
      o.x = acc[g][db][0]; o.y = acc[g][db][1];
      o.z = acc[g][db][2]; o.w = acc[g][db][3];
      *(float4*)(op + db*16) = o;
    }
    if (lg == 0) {
      size_t row = (size_t)h*S_LEN + qrow;
      lmW[(size_t)p*131072 + row]         = acc_l[g][0];  // l
      lmW[(size_t)p*131072 + 65536 + row] = m_run[g];     // m (exp2 domain)
    }
  }
}

// ---- merge: O = (A0*2^(m0-m) + A1*2^(m1-m)) / (l0*2^(m0-m) + l1*2^(m1-m)) ----
__global__ __launch_bounds__(256) void merge2(const float* __restrict__ A1,
                                              const float* __restrict__ lmW,
                                              float* __restrict__ O) {
  size_t idx = (size_t)blockIdx.x*256 + threadIdx.x;   // one float4 of O
  size_t sh = idx >> 5;          // s*16 + h
  int hh = (int)(sh & 15);
  int ss = (int)(sh >> 4);
  size_t row = (size_t)hh*S_LEN + ss;
  float l0 = lmW[row],          m0 = lmW[65536 + row];
  float l1 = lmW[131072 + row], m1 = lmW[196608 + row];
  float m  = fmaxf(m0, m1);
  float w0 = exp2f(m0 - m), w1 = exp2f(m1 - m);
  float inv = 1.0f / (l0*w0 + l1*w1);
  float4 a0 = *(const float4*)(O  + idx*4);
  float4 a1 = *(const float4*)(A1 + idx*4);
  float4 o;
  o.x = (a0.x*w0 + a1.x*w1)*inv;
  o.y = (a0.y*w0 + a1.y*w1)*inv;
  o.z = (a0.z*w0 + a1.z*w1)*inv;
  o.w = (a0.w*w0 + a1.w*w1)*inv;
  *(float4*)(O + idx*4) = o;
}

extern "C" void kernel_launch(void* const* d_in, const int* in_sizes, int n_in,
                              void* d_out, int out_size, void* d_ws, size_t ws_size,
                              hipStream_t stream) {
  const float* Q = (const float*)d_in[0];
  const float* K = (const float*)d_in[1];
  const float* V = (const float*)d_in[2];
  float* O = (float*)d_out;
  bf16_t* Kp = (bf16_t*)d_ws;                   // 16.78 MB
  bf16_t* Vp = Kp + (size_t)8388608;            // 16.78 MB
  float*  A1 = (float*)(Vp + (size_t)8388608);  // 33.55 MB raw partial 1
  float*  lm = A1 + (size_t)8388608;            // 1.05 MB (4 planes of 65536)
  prep_k<<<dim3(NT, NH), 256, 0, stream>>>(K, Kp);
  prep_v<<<dim3(NT, NH), 256, 0, stream>>>(V, Vp);
  attn_fwd<<<dim3(2048), 128, 0, stream>>>(Q, Kp, Vp, O, A1, lm);
  merge2<<<dim3(8192), 256, 0, stream>>>(A1, lm, O);
}